// Round 1
// baseline (214.502 us; speedup 1.0000x reference)
//
#include <hip/hip_runtime.h>
#include <math.h>

// Problem constants
#define BB 65536
#define II 512
#define HH 128
#define TT 2
#define ES 2
#define EC 4
#define NS 6            // expert slots per task (ES + EC)
#define NJ 12           // per task: 6 gate-logit cols + 6 s-value cols
#define NCOL 24         // TT * NJ
#define NCOLP 32        // padded to MFMA col tiles (cols 24..31 = 0)
#define FF (NS * HH)    // 768 gate-input features per task
#define KSTEPS (II / 32) // 16 MFMA k-steps

typedef _Float16 f16;
typedef f16   half8 __attribute__((ext_vector_type(8)));
typedef float f32x4 __attribute__((ext_vector_type(4)));

// Shared (lane-group g, slot s) -> logical k map for BOTH A and B fragments:
//   k(g, s) = g*4 + (s>>2)*16 + (s&3)
// A-side: slot s comes from two float4 loads (k0+g*4+0..3, k0+g*4+16+..19).
// B-side: kernel 1 scatters M[k][j] to the matching slot. Because the map is
// identical on both operands, the MFMA contraction is invariant to the
// instruction's true internal k-order. Only C/D layout (HW-verified:
// col=lane&15, row=(lane>>4)*4+reg) must be right.

// ---------------------------------------------------------------------------
// Kernel 1: fold all weights into f16 B-fragments Mfrag[16][2][64][8] (32 KB)
// and d[NCOL] (f32). Grid: II+1 thin blocks (block II = bias row), 256 thr.
// Compute path unchanged from the verified fp32 kernel; only the store layout
// changed (frag-scatter f16 instead of M[i][col] f32).
// ---------------------------------------------------------------------------
#define FFP (FF + 4)   // 772: padded wgt row

__global__ __launch_bounds__(256) void cgc_precompute(
    const float* __restrict__ Wc, const float* __restrict__ bc,
    const float* __restrict__ Ws, const float* __restrict__ bs,
    const float* __restrict__ Wg, const float* __restrict__ bg,
    const float* __restrict__ Wt,
    f16* __restrict__ Mfrag, float* __restrict__ d)
{
    __shared__ float wrow[TT * FF];        // 6 KB
    __shared__ float wgt[TT * NS * FFP];   // 37.1 KB  [t][e][f]
    __shared__ float wt[TT * HH];          // 1 KB
    __shared__ float red[NCOL][9];

    const int blk = blockIdx.x;
    const bool isd = (blk == II);
    const int i   = blk;
    const int tid = threadIdx.x;

    // Stage Wg transposed: coalesced float4 global reads, scattered b32 writes
    {
        const float4* Wg4 = (const float4*)Wg;
        for (int idx = tid; idx < TT * FF * NS / 4; idx += 256) {
            const float4 v = Wg4[idx];
            const int p0 = idx * 4;
            const float vv[4] = {v.x, v.y, v.z, v.w};
            #pragma unroll
            for (int u = 0; u < 4; ++u) {
                const int p = p0 + u;               // ((t*FF + f)*NS + e)
                const int t = p / (FF * NS);
                const int r = p % (FF * NS);
                const int f = r / NS;
                const int e = r % NS;
                wgt[(t * NS + e) * FFP + f] = vv[u];
            }
        }
        if (tid < TT * HH / 4)
            ((float4*)wt)[tid] = ((const float4*)Wt)[tid];
    }
    // Stage W-row (or bias vector): 384 float4, coalesced per 32-f4 segment.
    {
        const float4* Ws4 = (const float4*)Ws;
        const float4* Wc4 = (const float4*)Wc;
        const float4* bs4 = (const float4*)bs;
        const float4* bc4 = (const float4*)bc;
        float4* wr4 = (float4*)wrow;
        for (int idx = tid; idx < TT * FF / 4; idx += 256) {
            const int t   = idx / (FF / 4);
            const int rem = idx % (FF / 4);      // 0..191
            const int s   = rem >> 5;            // slot 0..5
            const int h4  = rem & 31;
            float4 v;
            if (isd) {
                v = (s < ES) ? bs4[(t * ES + s) * 32 + h4]
                             : bc4[(s - ES) * 32 + h4];
            } else {
                v = (s < ES) ? Ws4[((t * ES + s) * II + i) * 32 + h4]
                             : Wc4[((s - ES) * II + i) * 32 + h4];
            }
            wr4[idx] = v;
        }
    }
    __syncthreads();

    // 192 active threads: col = tid/8 (0..23), fp = tid%8 (f-partition)
    const int col = tid >> 3;
    const int fp  = tid & 7;
    if (col < NCOL) {
        const int t = col / NJ;
        const int j = col % NJ;
        float acc = 0.0f;
        if (j < NS) {
            const float* wr  = &wrow[t * FF];
            const float* wgr = &wgt[(t * NS + j) * FFP];
            #pragma unroll 4
            for (int ff = 0; ff < FF / 8; ++ff) {
                const int f = ff * 8 + fp;       // interleaved partition
                acc = fmaf(wr[f], wgr[f], acc);
            }
        } else {
            const int s = j - NS;
            const float* wr  = &wrow[t * FF + s * HH];
            const float* wtr = &wt[t * HH];
            #pragma unroll
            for (int hh = 0; hh < HH / 8; ++hh) {
                const int h = hh * 8 + fp;
                acc = fmaf(wr[h], wtr[h], acc);
            }
        }
        red[col][fp] = acc;
    }
    __syncthreads();

    if (tid < NCOLP) {
        float v = 0.0f;
        if (tid < NCOL) {
            #pragma unroll
            for (int p = 0; p < 8; ++p) v += red[tid][p];
        }
        if (isd) {
            if (tid < NCOL) {
                const int t = tid / NJ, j = tid % NJ;
                if (j < NS) v += bg[t * NS + j];
                d[tid] = v;
            }
        } else {
            // frag-scatter: k = i, col j = tid (j in 24..31 stores zero pad)
            const int step = i >> 5;
            const int kk   = i & 31;
            const int g    = (kk >> 2) & 3;                  // lane group
            const int s    = ((kk >> 4) << 2) | (kk & 3);    // slot 0..7
            const int ct   = tid >> 4;                       // col tile
            const int ln   = g * 16 + (tid & 15);            // lane
            Mfrag[((((step * 2 + ct) * 64) + ln) << 3) + s] = (f16)v;
        }
    }
}

// ---------------------------------------------------------------------------
// Kernel 2: z[b][0:24] = x[b][:] @ M  via f16 MFMA (f32 accumulate), then
// per-task softmax(6) . s-values + bt.
// 512 blocks x 256 thr (4 waves). Wave w owns rows [blk*128 + w*32, +32)
// (2 row-tiles of 16) over the FULL K=512: no cross-wave reduction.
// Per k-step: 4x global_load_dwordx4 of x (16 rows x 64 B contiguous per
// instr -> full-line coalesced), cvt->f16 in regs, B-frags from LDS (2x
// ds_read_b128), 4 MFMA. x read exactly once from HBM: BW-bound by design.
// ---------------------------------------------------------------------------
#define RT 2            // row-tiles per wave
#define ZP 25           // zbuf row pad

union Sh2 {
    uint4 bfrag[KSTEPS * 2 * 64];   // 32 KB f16 B-fragments
    float zbuf[128][ZP];            // 12.8 KB epilogue buffer (aliased)
};

__device__ __forceinline__ half8 uint4_as_half8(uint4 u) {
    union { uint4 u; half8 h; } c; c.u = u; return c.h;
}

__global__ __launch_bounds__(256, 2) void cgc_main(
    const float* __restrict__ x,
    const f16* __restrict__ Mfrag,
    const float* __restrict__ dg,
    const float* __restrict__ bt,
    float* __restrict__ out)
{
    __shared__ Sh2 sh;

    const int tid  = threadIdx.x;
    const int wv   = tid >> 6;
    const int lane = tid & 63;
    const int cl   = lane & 15;     // A-row-in-tile / C-col-in-tile
    const int g    = lane >> 4;     // k lane-group (and C row-quad)
    const int r0   = blockIdx.x * 128;

    // Stage B-fragments (32 KB, L2-resident after first block touches it)
    {
        const uint4* Mf4 = (const uint4*)Mfrag;
        #pragma unroll
        for (int it = 0; it < (KSTEPS * 2 * 64) / 256; ++it)
            sh.bfrag[it * 256 + tid] = Mf4[it * 256 + tid];
    }
    __syncthreads();

    f32x4 acc[RT][2];
    #pragma unroll
    for (int rt = 0; rt < RT; ++rt)
        #pragma unroll
        for (int ct = 0; ct < 2; ++ct)
            acc[rt][ct] = (f32x4){0.f, 0.f, 0.f, 0.f};

    // Per-lane x base: row = r0 + wv*32 + rt*16 + cl, col base = g*4.
    // All k-step offsets (s*128 B, +64 B) fold into the load's imm offset.
    const float* xp0 = x + (size_t)(r0 + wv * 32 + cl) * II + g * 4;
    const float* xp1 = xp0 + 16 * II;

    #pragma unroll 4
    for (int s = 0; s < KSTEPS; ++s) {
        const uint4* bp = &sh.bfrag[s * 128 + lane];
        const half8 b0 = uint4_as_half8(bp[0]);
        const half8 b1 = uint4_as_half8(bp[64]);
        #pragma unroll
        for (int rt = 0; rt < RT; ++rt) {
            const float* xp = (rt == 0 ? xp0 : xp1) + s * 32;
            const f32x4 xa = *(const f32x4*)(xp);        // k = g*4+0..3
            const f32x4 xb = *(const f32x4*)(xp + 16);   // k = g*4+16..19
            half8 a;
            a[0] = (f16)xa[0]; a[1] = (f16)xa[1];
            a[2] = (f16)xa[2]; a[3] = (f16)xa[3];
            a[4] = (f16)xb[0]; a[5] = (f16)xb[1];
            a[6] = (f16)xb[2]; a[7] = (f16)xb[3];
            acc[rt][0] = __builtin_amdgcn_mfma_f32_16x16x32_f16(a, b0, acc[rt][0], 0, 0, 0);
            acc[rt][1] = __builtin_amdgcn_mfma_f32_16x16x32_f16(a, b1, acc[rt][1], 0, 0, 0);
        }
    }

    // d-bias per column this lane owns
    const float dv0 = dg[cl];                        // cols 0..15
    const float dv1 = (cl < 8) ? dg[16 + cl] : 0.f;  // cols 16..23 (24+ pad)

    __syncthreads();   // all waves done reading bfrag before zbuf overwrite

    // C/D layout (HW-verified m89): col = lane&15, row = (lane>>4)*4 + reg
    #pragma unroll
    for (int rt = 0; rt < RT; ++rt) {
        const int rr = wv * 32 + rt * 16 + g * 4;
        #pragma unroll
        for (int q = 0; q < 4; ++q) {
            sh.zbuf[rr + q][cl] = acc[rt][0][q] + dv0;
            if (cl < 8)
                sh.zbuf[rr + q][16 + cl] = acc[rt][1][q] + dv1;
        }
    }
    __syncthreads();

    // Epilogue: thread -> (row = tid&127, task = tid>>7)
    {
        const int row = tid & 127;
        const int t   = tid >> 7;
        const float* zr = &sh.zbuf[row][t * NJ];
        float m = zr[0];
        #pragma unroll
        for (int j = 1; j < NS; ++j) m = fmaxf(m, zr[j]);
        float ssum = 0.f, o = 0.f;
        #pragma unroll
        for (int j = 0; j < NS; ++j) {
            const float e = __expf(zr[j] - m);
            ssum += e;
            o += e * zr[NS + j];
        }
        out[t * BB + r0 + row] = o / ssum + bt[t];
    }
}

// ---------------------------------------------------------------------------
extern "C" void kernel_launch(void* const* d_in, const int* in_sizes, int n_in,
                              void* d_out, int out_size, void* d_ws, size_t ws_size,
                              hipStream_t stream)
{
    const float* x  = (const float*)d_in[0];
    const float* Wc = (const float*)d_in[1];
    const float* bc = (const float*)d_in[2];
    const float* Ws = (const float*)d_in[3];
    const float* bs = (const float*)d_in[4];
    const float* Wg = (const float*)d_in[5];
    const float* bg = (const float*)d_in[6];
    const float* Wt = (const float*)d_in[7];
    const float* bt = (const float*)d_in[8];
    float* out = (float*)d_out;

    f16*   Mfrag = (f16*)d_ws;                               // 32 KB frags
    float* d     = (float*)((char*)d_ws + KSTEPS * 2 * 64 * 16); // d[NCOL]

    cgc_precompute<<<dim3(II + 1), dim3(256), 0, stream>>>(
        Wc, bc, Ws, bs, Wg, bg, Wt, Mfrag, d);
    cgc_main<<<dim3(BB / 128), dim3(256), 0, stream>>>(
        x, Mfrag, d, bt, out);
}

// Round 5
// 213.562 us; speedup vs baseline: 1.0044x; 1.0044x over previous
//
#include <hip/hip_runtime.h>
#include <math.h>

// Problem constants
#define BB 65536
#define II 512
#define HH 128
#define TT 2
#define ES 2
#define EC 4
#define NS 6            // expert slots per task (ES + EC)
#define NJ 12           // per task: 6 gate-logit cols + 6 s-value cols
#define NCOL 24         // TT * NJ
#define NCOLP 32        // padded to MFMA col tiles (cols 24..31 = 0)
#define FF (NS * HH)    // 768 gate-input features per task
#define KSTEPS (II / 32) // 16 MFMA k-steps

typedef _Float16 f16;
typedef f16   half8 __attribute__((ext_vector_type(8)));
typedef float f32x4 __attribute__((ext_vector_type(4)));

// Shared (lane-group g, slot s) -> logical k map for BOTH A and B fragments:
//   k(g, s) = g*4 + (s>>2)*16 + (s&3)
// Identical map on both operands -> contraction invariant to the MFMA's
// internal k-order. C/D layout (HW-verified + harness-verified R1):
// col = lane&15, row = (lane>>4)*4 + reg.

// ---------------------------------------------------------------------------
// Kernel 1: fold all weights into f16 B-fragments Mfrag[16][2][64][8] (32 KB)
// and d[NCOL] (f32). Grid: II+1 thin blocks (block II = bias row), 256 thr.
// UNCHANGED from R1 (harness-verified).
// ---------------------------------------------------------------------------
#define FFP (FF + 4)   // 772: padded wgt row

__global__ __launch_bounds__(256) void cgc_precompute(
    const float* __restrict__ Wc, const float* __restrict__ bc,
    const float* __restrict__ Ws, const float* __restrict__ bs,
    const float* __restrict__ Wg, const float* __restrict__ bg,
    const float* __restrict__ Wt,
    f16* __restrict__ Mfrag, float* __restrict__ d)
{
    __shared__ float wrow[TT * FF];        // 6 KB
    __shared__ float wgt[TT * NS * FFP];   // 37.1 KB  [t][e][f]
    __shared__ float wt[TT * HH];          // 1 KB
    __shared__ float red[NCOL][9];

    const int blk = blockIdx.x;
    const bool isd = (blk == II);
    const int i   = blk;
    const int tid = threadIdx.x;

    // Stage Wg transposed: coalesced float4 global reads, scattered b32 writes
    {
        const float4* Wg4 = (const float4*)Wg;
        for (int idx = tid; idx < TT * FF * NS / 4; idx += 256) {
            const float4 v = Wg4[idx];
            const int p0 = idx * 4;
            const float vv[4] = {v.x, v.y, v.z, v.w};
            #pragma unroll
            for (int u = 0; u < 4; ++u) {
                const int p = p0 + u;               // ((t*FF + f)*NS + e)
                const int t = p / (FF * NS);
                const int r = p % (FF * NS);
                const int f = r / NS;
                const int e = r % NS;
                wgt[(t * NS + e) * FFP + f] = vv[u];
            }
        }
        if (tid < TT * HH / 4)
            ((float4*)wt)[tid] = ((const float4*)Wt)[tid];
    }
    // Stage W-row (or bias vector): 384 float4, coalesced per 32-f4 segment.
    {
        const float4* Ws4 = (const float4*)Ws;
        const float4* Wc4 = (const float4*)Wc;
        const float4* bs4 = (const float4*)bs;
        const float4* bc4 = (const float4*)bc;
        float4* wr4 = (float4*)wrow;
        for (int idx = tid; idx < TT * FF / 4; idx += 256) {
            const int t   = idx / (FF / 4);
            const int rem = idx % (FF / 4);      // 0..191
            const int s   = rem >> 5;            // slot 0..5
            const int h4  = rem & 31;
            float4 v;
            if (isd) {
                v = (s < ES) ? bs4[(t * ES + s) * 32 + h4]
                             : bc4[(s - ES) * 32 + h4];
            } else {
                v = (s < ES) ? Ws4[((t * ES + s) * II + i) * 32 + h4]
                             : Wc4[((s - ES) * II + i) * 32 + h4];
            }
            wr4[idx] = v;
        }
    }
    __syncthreads();

    // 192 active threads: col = tid/8 (0..23), fp = tid%8 (f-partition)
    const int col = tid >> 3;
    const int fp  = tid & 7;
    if (col < NCOL) {
        const int t = col / NJ;
        const int j = col % NJ;
        float acc = 0.0f;
        if (j < NS) {
            const float* wr  = &wrow[t * FF];
            const float* wgr = &wgt[(t * NS + j) * FFP];
            #pragma unroll 4
            for (int ff = 0; ff < FF / 8; ++ff) {
                const int f = ff * 8 + fp;       // interleaved partition
                acc = fmaf(wr[f], wgr[f], acc);
            }
        } else {
            const int s = j - NS;
            const float* wr  = &wrow[t * FF + s * HH];
            const float* wtr = &wt[t * HH];
            #pragma unroll
            for (int hh = 0; hh < HH / 8; ++hh) {
                const int h = hh * 8 + fp;
                acc = fmaf(wr[h], wtr[h], acc);
            }
        }
        red[col][fp] = acc;
    }
    __syncthreads();

    if (tid < NCOLP) {
        float v = 0.0f;
        if (tid < NCOL) {
            #pragma unroll
            for (int p = 0; p < 8; ++p) v += red[tid][p];
        }
        if (isd) {
            if (tid < NCOL) {
                const int t = tid / NJ, j = tid % NJ;
                if (j < NS) v += bg[t * NS + j];
                d[tid] = v;
            }
        } else {
            // frag-scatter: k = i, col j = tid (j in 24..31 stores zero pad)
            const int step = i >> 5;
            const int kk   = i & 31;
            const int g    = (kk >> 2) & 3;                  // lane group
            const int s    = ((kk >> 4) << 2) | (kk & 3);    // slot 0..7
            const int ct   = tid >> 4;                       // col tile
            const int ln   = g * 16 + (tid & 15);            // lane
            Mfrag[((((step * 2 + ct) * 64) + ln) << 3) + s] = (f16)v;
        }
    }
}

// ---------------------------------------------------------------------------
// Kernel 2: z[b][0:24] = x[b][:] @ M  via f16 MFMA (f32 accumulate), then
// per-task softmax(6) . s-values + bt.
// R2 change: RT=1, 64 rows/block, grid 1024 -> 4 blocks/CU (16 waves/CU,
// was 8) for better latency hiding on the streaming x read; full k-unroll
// with 1-deep explicit prefetch. Per wave: 16 rows, full K=512, no
// cross-wave reduction. x read exactly once from HBM/L3: BW-bound by design.
// ---------------------------------------------------------------------------
#define ROWSB 64        // rows per block (16 per wave)
#define ZP 25           // zbuf row pad

union Sh2 {
    uint4 bfrag[KSTEPS * 2 * 64];   // 32 KB f16 B-fragments
    float zbuf[ROWSB][ZP];          // 6.4 KB epilogue buffer (aliased)
};

__device__ __forceinline__ half8 uint4_as_half8(uint4 u) {
    union { uint4 u; half8 h; } c; c.u = u; return c.h;
}

__global__ __launch_bounds__(256, 4) void cgc_main(
    const float* __restrict__ x,
    const f16* __restrict__ Mfrag,
    const float* __restrict__ dg,
    const float* __restrict__ bt,
    float* __restrict__ out)
{
    __shared__ Sh2 sh;

    const int tid  = threadIdx.x;
    const int wv   = tid >> 6;
    const int lane = tid & 63;
    const int cl   = lane & 15;     // A-row-in-tile / C-col-in-tile
    const int g    = lane >> 4;     // k lane-group (and C row-quad)
    const int r0   = blockIdx.x * ROWSB;

    // Stage B-fragments (32 KB, L2/L3-resident: 8 coalesced uint4 per thread)
    {
        const uint4* Mf4 = (const uint4*)Mfrag;
        #pragma unroll
        for (int it = 0; it < (KSTEPS * 2 * 64) / 256; ++it)
            sh.bfrag[it * 256 + tid] = Mf4[it * 256 + tid];
    }
    __syncthreads();

    f32x4 acc0 = (f32x4){0.f, 0.f, 0.f, 0.f};
    f32x4 acc1 = (f32x4){0.f, 0.f, 0.f, 0.f};

    // Per-lane x base: row = r0 + wv*16 + cl, col base = g*4.
    // k-step offsets (s*128 B, +64 B) fold into the load's imm offset.
    const float* xp = x + (size_t)(r0 + wv * 16 + cl) * II + g * 4;

    f32x4 xa = *(const f32x4*)(xp);        // k = g*4+0..3
    f32x4 xb = *(const f32x4*)(xp + 16);   // k = g*4+16..19

    #pragma unroll
    for (int s = 0; s < KSTEPS; ++s) {
        f32x4 na, nb;
        if (s + 1 < KSTEPS) {
            na = *(const f32x4*)(xp + (s + 1) * 32);
            nb = *(const f32x4*)(xp + (s + 1) * 32 + 16);
        }
        const uint4* bp = &sh.bfrag[s * 128 + lane];
        const half8 b0 = uint4_as_half8(bp[0]);
        const half8 b1 = uint4_as_half8(bp[64]);
        half8 a;
        a[0] = (f16)xa[0]; a[1] = (f16)xa[1];
        a[2] = (f16)xa[2]; a[3] = (f16)xa[3];
        a[4] = (f16)xb[0]; a[5] = (f16)xb[1];
        a[6] = (f16)xb[2]; a[7] = (f16)xb[3];
        acc0 = __builtin_amdgcn_mfma_f32_16x16x32_f16(a, b0, acc0, 0, 0, 0);
        acc1 = __builtin_amdgcn_mfma_f32_16x16x32_f16(a, b1, acc1, 0, 0, 0);
        xa = na; xb = nb;
    }

    // d-bias per column this lane owns
    const float dv0 = dg[cl];                        // cols 0..15
    const float dv1 = (cl < 8) ? dg[16 + cl] : 0.f;  // cols 16..23 (24+ pad)

    __syncthreads();   // all waves done reading bfrag before zbuf overwrite

    // C/D layout: col = lane&15, row = (lane>>4)*4 + reg
    {
        const int rr = wv * 16 + g * 4;
        #pragma unroll
        for (int q = 0; q < 4; ++q) {
            sh.zbuf[rr + q][cl] = acc0[q] + dv0;
            if (cl < 8)
                sh.zbuf[rr + q][16 + cl] = acc1[q] + dv1;
        }
    }
    __syncthreads();

    // Epilogue: threads 0..127 -> (row = tid&63, task = tid>>6)
    if (tid < ROWSB * TT) {
        const int row = tid & (ROWSB - 1);
        const int t   = tid >> 6;
        const float* zr = &sh.zbuf[row][t * NJ];
        float m = zr[0];
        #pragma unroll
        for (int j = 1; j < NS; ++j) m = fmaxf(m, zr[j]);
        float ssum = 0.f, o = 0.f;
        #pragma unroll
        for (int j = 0; j < NS; ++j) {
            const float e = __expf(zr[j] - m);
            ssum += e;
            o += e * zr[NS + j];
        }
        out[t * BB + r0 + row] = o / ssum + bt[t];
    }
}

// ---------------------------------------------------------------------------
extern "C" void kernel_launch(void* const* d_in, const int* in_sizes, int n_in,
                              void* d_out, int out_size, void* d_ws, size_t ws_size,
                              hipStream_t stream)
{
    const float* x  = (const float*)d_in[0];
    const float* Wc = (const float*)d_in[1];
    const float* bc = (const float*)d_in[2];
    const float* Ws = (const float*)d_in[3];
    const float* bs = (const float*)d_in[4];
    const float* Wg = (const float*)d_in[5];
    const float* bg = (const float*)d_in[6];
    const float* Wt = (const float*)d_in[7];
    const float* bt = (const float*)d_in[8];
    float* out = (float*)d_out;

    f16*   Mfrag = (f16*)d_ws;                               // 32 KB frags
    float* d     = (float*)((char*)d_ws + KSTEPS * 2 * 64 * 16); // d[NCOL]

    cgc_precompute<<<dim3(II + 1), dim3(256), 0, stream>>>(
        Wc, bc, Ws, bs, Wg, bg, Wt, Mfrag, d);
    cgc_main<<<dim3(BB / ROWSB), dim3(256), 0, stream>>>(
        x, Mfrag, d, bt, out);
}